// Round 3
// baseline (55.129 us; speedup 1.0000x reference)
//
#include <hip/hip_runtime.h>
#include <math.h>

// Problem constants (fixed by the reference setup)
constexpr int N = 4096;
constexpr int E = 128;
constexpr int H = 8;
constexpr int D = 16;      // E / H
constexpr int SPAN = 50;

// ---------------------------------------------------------------------------
// Kernel 1: fused projections  q = X@Wq+bq, k, v, and b = attn_bias@Wfe+bfe
// (unchanged from previous round)
// ---------------------------------------------------------------------------
__global__ __launch_bounds__(256) void proj_kernel(
    const float* __restrict__ query, const float* __restrict__ key,
    const float* __restrict__ value, const float* __restrict__ attn_bias,
    const float* __restrict__ Wq, const float* __restrict__ bq,
    const float* __restrict__ Wk, const float* __restrict__ bk,
    const float* __restrict__ Wv, const float* __restrict__ bv,
    const float* __restrict__ Wfe, const float* __restrict__ bfe,
    float* __restrict__ qo, float* __restrict__ ko,
    float* __restrict__ vo, float* __restrict__ bo_)
{
    __shared__ float xq[8][E];
    __shared__ float xk[8][E];
    __shared__ float xv[8][E];
    __shared__ float ab[8][H];

    const int tid  = threadIdx.x;
    const int col  = tid & 127;
    const int half = tid >> 7;
    const int row0 = blockIdx.x * 8;

    #pragma unroll
    for (int m = 0; m < 4; ++m) {
        const int e = tid + 256 * m;
        const int r = e >> 7, c = e & 127;
        xq[r][c] = query[(size_t)(row0 + r) * E + c];
        xk[r][c] = key  [(size_t)(row0 + r) * E + c];
        xv[r][c] = value[(size_t)(row0 + r) * E + c];
    }
    if (tid < 64) ab[tid >> 3][tid & 7] = attn_bias[(size_t)row0 * H + tid];
    __syncthreads();

    const int r0 = half * 4;
    float aq[4], ak[4], av[4], ai[4];
    {
        const float tq = bq[col], tk = bk[col], tv = bv[col], ti = bfe[col];
        #pragma unroll
        for (int r = 0; r < 4; ++r) { aq[r]=tq; ak[r]=tk; av[r]=tv; ai[r]=ti; }
    }

    for (int kk = 0; kk < E; kk += 4) {
        float wq[4], wk[4], wv[4];
        #pragma unroll
        for (int u = 0; u < 4; ++u) {
            wq[u] = Wq[(size_t)(kk + u) * E + col];
            wk[u] = Wk[(size_t)(kk + u) * E + col];
            wv[u] = Wv[(size_t)(kk + u) * E + col];
        }
        #pragma unroll
        for (int r = 0; r < 4; ++r) {
            float4 x;
            x = *(const float4*)&xq[r0 + r][kk];
            aq[r] = fmaf(x.x, wq[0], aq[r]); aq[r] = fmaf(x.y, wq[1], aq[r]);
            aq[r] = fmaf(x.z, wq[2], aq[r]); aq[r] = fmaf(x.w, wq[3], aq[r]);
            x = *(const float4*)&xk[r0 + r][kk];
            ak[r] = fmaf(x.x, wk[0], ak[r]); ak[r] = fmaf(x.y, wk[1], ak[r]);
            ak[r] = fmaf(x.z, wk[2], ak[r]); ak[r] = fmaf(x.w, wk[3], ak[r]);
            x = *(const float4*)&xv[r0 + r][kk];
            av[r] = fmaf(x.x, wv[0], av[r]); av[r] = fmaf(x.y, wv[1], av[r]);
            av[r] = fmaf(x.z, wv[2], av[r]); av[r] = fmaf(x.w, wv[3], av[r]);
        }
    }
    #pragma unroll
    for (int hh = 0; hh < H; ++hh) {
        const float wfe = Wfe[(size_t)hh * E + col];
        #pragma unroll
        for (int r = 0; r < 4; ++r)
            ai[r] = fmaf(ab[r0 + r][hh], wfe, ai[r]);
    }

    #pragma unroll
    for (int r = 0; r < 4; ++r) {
        const size_t o = (size_t)(row0 + r0 + r) * E + col;
        qo[o] = aq[r]; ko[o] = ak[r]; vo[o] = av[r]; bo_[o] = ai[r];
    }
}

// ---------------------------------------------------------------------------
// Kernel 2: fused banded attention + output projection.
// One block (512 threads = 8 waves) per 8-row tile; wave wv handles head wv.
// Attention phase is barrier-free (all LDS state is per-wave). Then one
// barrier, Wo is staged transposed in the (dead) V region of LDS, and
// 256 threads do the 8-row out-projection.
// ---------------------------------------------------------------------------
__global__ __launch_bounds__(512, 4) void attn_out_kernel(
    const float* __restrict__ q, const float* __restrict__ k,
    const float* __restrict__ v, const float* __restrict__ b,
    const float* __restrict__ Wo, const float* __restrict__ bop,
    float* __restrict__ out)
{
    // smem layout (floats):
    //   [0, 16896)        : V tiles as [8 heads][128 rows][4 float4]  (64KB)
    //                       reused after barrier as WoT[128 cols][132]
    //   [16896, 18688)    : exp-weights ew [8 heads][2][112]
    //   [18688, 19712)    : attn tile [8 rows][128 cols]
    __shared__ __align__(16) float smem[19712];
    float4* vt4 = (float4*)smem;
    float*  ewp = smem + 16896;
    float*  at  = smem + 16896 + 1792;

    const int tid  = threadIdx.x;
    const int lane = tid & 63;
    const int wv   = __builtin_amdgcn_readfirstlane(tid >> 6);   // head
    const int i0   = blockIdx.x * 8;
    const int base = i0 - SPAN;

    // zero-pad ew[101..111] (PV loop runs w up to 111 branchlessly)
    if (lane < 11) {
        ewp[(wv * 2 + 0) * 112 + 101 + lane] = 0.f;
        ewp[(wv * 2 + 1) * 112 + 101 + lane] = 0.f;
    }

    // ---- stage V rows [base, base+128) for head wv (per-wave, no barrier) --
    {
        const int x  = lane & 3;    // float4 quad within row
        const int r0 = lane >> 2;   // 16 rows per instruction
        #pragma unroll
        for (int rep = 0; rep < 8; ++rep) {
            const int r = rep * 16 + r0;
            int j = base + r;
            j = j < 0 ? 0 : (j > N - 1 ? N - 1 : j);
            vt4[wv * 512 + r * 4 + x] =
                ((const float4*)(v + (size_t)j * E + wv * D))[x];
        }
    }

    // ---- K/B(feature) rows for this lane's two positions -> registers ----
    const int p0 = base + lane;
    const int p1 = p0 + 64;                 // >= i0+14 >= 14, never negative
    const bool in0 = (p0 >= 0) && (p0 < N);
    const bool in1 = (p1 < N);
    const int c0 = p0 < 0 ? 0 : (p0 > N - 1 ? N - 1 : p0);
    const int c1 = p1 > N - 1 ? N - 1 : p1;

    float k0[16], k1[16], g0[16], g1[16];
    {
        const float4* kp0 = (const float4*)(k + (size_t)c0 * E + wv * D);
        const float4* kp1 = (const float4*)(k + (size_t)c1 * E + wv * D);
        const float4* gp0 = (const float4*)(b + (size_t)c0 * E + wv * D);
        const float4* gp1 = (const float4*)(b + (size_t)c1 * E + wv * D);
        #pragma unroll
        for (int x = 0; x < 4; ++x) {
            float4 t;
            t = kp0[x]; k0[4*x]=t.x; k0[4*x+1]=t.y; k0[4*x+2]=t.z; k0[4*x+3]=t.w;
            t = kp1[x]; k1[4*x]=t.x; k1[4*x+1]=t.y; k1[4*x+2]=t.z; k1[4*x+3]=t.w;
            t = gp0[x]; g0[4*x]=t.x; g0[4*x+1]=t.y; g0[4*x+2]=t.z; g0[4*x+3]=t.w;
            t = gp1[x]; g1[4*x]=t.x; g1[4*x+1]=t.y; g1[4*x+2]=t.z; g1[4*x+3]=t.w;
        }
    }

    const float scale = 1.0f / 64.0f;       // 1/sqrt(4096)
    const int d0 = lane & 3;                // float4 quad of the head dim
    const int g  = lane >> 2;               // window group (16 groups)

    #pragma unroll
    for (int r = 0; r < 8; ++r) {
        // Q and B(query) rows: wave-uniform addresses -> scalar loads
        const float* qp = q + (size_t)(i0 + r) * E + wv * D;
        const float* bp = b + (size_t)(i0 + r) * E + wv * D;

        float sq0 = 0.f, sq1 = 0.f, sb0 = 0.f, sb1 = 0.f;
        #pragma unroll
        for (int x = 0; x < 16; ++x) {
            const float qv = qp[x];
            const float bv = bp[x];
            sq0 = fmaf(qv, k0[x], sq0);
            sq1 = fmaf(qv, k1[x], sq1);
            sb0 = fmaf(bv, g0[x], sb0);
            sb1 = fmaf(bv, g1[x], sb1);
        }
        // window membership: w0 = lane-r in [0,63-r], w1 = 64+lane-r <= 100
        const bool ok0 = in0 && (lane >= r);
        const bool ok1 = in1 && (lane <= r + 36);
        const float s0 = ok0 ? sq0 * scale + sb0 : -INFINITY;
        const float s1 = ok1 ? sq1 * scale + sb1 : -INFINITY;

        // no max-subtraction: scores are O(10), exp() is safe in fp32, and
        // softmax without the shift is mathematically identical.
        const float e0 = __expf(s0);   // -inf -> 0
        const float e1 = __expf(s1);

        float* ew = ewp + (wv * 2 + (r & 1)) * 112;
        if (lane >= r)      ew[lane - r]      = e0;
        if (lane <= r + 36) ew[64 + lane - r] = e1;

        // PV: lane = (d0, g); w = it*16 + g; prob-sum folded into the reduce
        float ax = 0.f, ay = 0.f, az = 0.f, aw = 0.f, as = 0.f;
        #pragma unroll
        for (int it = 0; it < 7; ++it) {
            const int w = it * 16 + g;
            const float p = ew[w];
            const float4 vv = vt4[wv * 512 + (w + r) * 4 + d0];
            ax = fmaf(p, vv.x, ax); ay = fmaf(p, vv.y, ay);
            az = fmaf(p, vv.z, az); aw = fmaf(p, vv.w, aw);
            as += p;
        }
        #pragma unroll
        for (int off = 4; off <= 32; off <<= 1) {
            ax += __shfl_xor(ax, off);
            ay += __shfl_xor(ay, off);
            az += __shfl_xor(az, off);
            aw += __shfl_xor(aw, off);
            as += __shfl_xor(as, off);
        }
        if (g == 0) {
            const float inv = 1.0f / as;
            ((float4*)&at[r * E + wv * D])[d0] =
                make_float4(ax * inv, ay * inv, az * inv, aw * inv);
        }
    }

    __syncthreads();

    // ---- stage Wo transposed into the dead V region: WoT[col][132] ----
    {
        const float4* WoV = (const float4*)Wo;
        #pragma unroll
        for (int m = 0; m < 8; ++m) {
            const int f = tid + 512 * m;      // 4096 float4 = all of Wo
            const float4 w4 = WoV[f];
            const int row = f >> 5;           // Wo row (k index)
            const int c   = (f & 31) * 4;     // first of 4 columns
            smem[(c + 0) * 132 + row] = w4.x;
            smem[(c + 1) * 132 + row] = w4.y;
            smem[(c + 2) * 132 + row] = w4.z;
            smem[(c + 3) * 132 + row] = w4.w;
        }
    }
    __syncthreads();

    // ---- out-projection: 256 threads, thread = (col, 4-row group) ----
    if (tid < 256) {
        const int col = tid & 127;
        const int rq  = tid >> 7;
        float o0, o1, o2, o3;
        o0 = o1 = o2 = o3 = bop[col];
        #pragma unroll 8
        for (int kk = 0; kk < E; kk += 4) {
            const float4 w4 = *(const float4*)&smem[col * 132 + kk];
            const float4 a0 = *(const float4*)&at[(4 * rq + 0) * E + kk];
            const float4 a1 = *(const float4*)&at[(4 * rq + 1) * E + kk];
            const float4 a2 = *(const float4*)&at[(4 * rq + 2) * E + kk];
            const float4 a3 = *(const float4*)&at[(4 * rq + 3) * E + kk];
            o0 = fmaf(a0.x, w4.x, o0); o0 = fmaf(a0.y, w4.y, o0);
            o0 = fmaf(a0.z, w4.z, o0); o0 = fmaf(a0.w, w4.w, o0);
            o1 = fmaf(a1.x, w4.x, o1); o1 = fmaf(a1.y, w4.y, o1);
            o1 = fmaf(a1.z, w4.z, o1); o1 = fmaf(a1.w, w4.w, o1);
            o2 = fmaf(a2.x, w4.x, o2); o2 = fmaf(a2.y, w4.y, o2);
            o2 = fmaf(a2.z, w4.z, o2); o2 = fmaf(a2.w, w4.w, o2);
            o3 = fmaf(a3.x, w4.x, o3); o3 = fmaf(a3.y, w4.y, o3);
            o3 = fmaf(a3.z, w4.z, o3); o3 = fmaf(a3.w, w4.w, o3);
        }
        const size_t ob = (size_t)(i0 + 4 * rq) * E + col;
        out[ob]         = o0;
        out[ob + E]     = o1;
        out[ob + 2 * E] = o2;
        out[ob + 3 * E] = o3;
    }
}

// ---------------------------------------------------------------------------
extern "C" void kernel_launch(void* const* d_in, const int* in_sizes, int n_in,
                              void* d_out, int out_size, void* d_ws, size_t ws_size,
                              hipStream_t stream) {
    const float* query     = (const float*)d_in[0];
    const float* key       = (const float*)d_in[1];
    const float* value     = (const float*)d_in[2];
    const float* attn_bias = (const float*)d_in[3];
    const float* Wq  = (const float*)d_in[4];
    const float* bq  = (const float*)d_in[5];
    const float* Wk  = (const float*)d_in[6];
    const float* bk  = (const float*)d_in[7];
    const float* Wv  = (const float*)d_in[8];
    const float* bv  = (const float*)d_in[9];
    const float* Wo  = (const float*)d_in[10];
    const float* bo  = (const float*)d_in[11];
    const float* Wfe = (const float*)d_in[12];
    const float* bfe = (const float*)d_in[13];

    float* ws = (float*)d_ws;
    const int NE = N * E;
    float* qw = ws;
    float* kw = ws + 1 * NE;
    float* vw = ws + 2 * NE;
    float* bw = ws + 3 * NE;

    proj_kernel<<<N / 8, 256, 0, stream>>>(query, key, value, attn_bias,
                                           Wq, bq, Wk, bk, Wv, bv, Wfe, bfe,
                                           qw, kw, vw, bw);
    attn_out_kernel<<<N / 8, 512, 0, stream>>>(qw, kw, vw, bw, Wo, bo,
                                               (float*)d_out);
}